// Round 3
// baseline (174.315 us; speedup 1.0000x reference)
//
#include <hip/hip_runtime.h>

typedef __attribute__((ext_vector_type(8))) short bf16x8;
typedef __attribute__((ext_vector_type(4))) float f32x4;
typedef __attribute__((ext_vector_type(4))) unsigned short u16x4;
typedef unsigned short u16;
typedef unsigned int u32;

static __device__ __forceinline__ u16 f2bf(float f) {
  u32 u = __float_as_uint(f);
  u32 r = (u + 0x7fffu + ((u >> 16) & 1u)) >> 16;  // RNE
  return (u16)r;
}

static __device__ __forceinline__ u32 cvt_pk(float lo, float hi) {
  u32 r;
  asm("v_cvt_pk_bf16_f32 %0, %1, %2" : "=v"(r) : "v"(lo), "v"(hi));
  return r;
}

#define GLDS16(g, l)                                                        \
  __builtin_amdgcn_global_load_lds(                                         \
      (const __attribute__((address_space(1))) u32*)(g),                    \
      (__attribute__((address_space(3))) u32*)(l), 16, 0, 0)

#define SC2F 0.18033688011112042f  // 0.125 * log2(e)

// ---------------- cast kernels ----------------
__global__ __launch_bounds__(256) void cast_x(const float* __restrict__ x,
                                              u16* __restrict__ xb) {
  int i = blockIdx.x * 256 + threadIdx.x;  // one thread per 8 elems
  const float4* xv = (const float4*)x;
  float4 a = xv[i * 2], b = xv[i * 2 + 1];
  bf16x8 o;
  o[0] = f2bf(a.x); o[1] = f2bf(a.y); o[2] = f2bf(a.z); o[3] = f2bf(a.w);
  o[4] = f2bf(b.x); o[5] = f2bf(b.y); o[6] = f2bf(b.z); o[7] = f2bf(b.w);
  *(bf16x8*)(xb + i * 8) = o;
}

// Wqkv_t[n][d], n = sel*1024 + h*64 + kk; value = W_sel[h][d][kk]
__global__ __launch_bounds__(256) void cast_wqkv(const float* __restrict__ wq,
                                                 const float* __restrict__ wk,
                                                 const float* __restrict__ wv,
                                                 u16* __restrict__ wt) {
  int tid = blockIdx.x * 256 + threadIdx.x;  // 3M
  int n = tid >> 10, d = tid & 1023;
  int sel = n >> 10, r = n & 1023, h = r >> 6, kk = r & 63;
  const float* src = sel == 0 ? wq : (sel == 1 ? wk : wv);
  wt[tid] = f2bf(src[h * 65536 + d * 64 + kk]);
}

// WOt[n][k] = W_O[k][n]
__global__ __launch_bounds__(256) void cast_wo(const float* __restrict__ wo,
                                               u16* __restrict__ wt) {
  int tid = blockIdx.x * 256 + threadIdx.x;  // 1M
  int n = tid >> 10, k = tid & 1023;
  wt[tid] = f2bf(wo[k * 1024 + n]);
}

// ---------------- GEMM: C = A(bf16)[M,K] * Bt(bf16)[N,K]^T ----------------
// 2-phase double-buffered staging (issue-early, one barrier per K-step).
// MODE 1: float C [M,N].  MODE 2: col<1024 -> Q*SC2F bf16; col<2048 -> K bf16;
//          col>=2048 -> Vt[(b*1024 + (col-2048))*2048 + s], row = b*2048+s.
template <int MODE>
__global__ __launch_bounds__(256) void gemm_bt(const u16* __restrict__ A,
                                               const u16* __restrict__ Bt,
                                               void* __restrict__ Cp,
                                               u16* __restrict__ Vt, int M,
                                               int N, int K) {
  const int t = threadIdx.x;
  const int lane = t & 63, w = t >> 6;
  const int lr = lane & 15, lg = lane >> 4;
  const int wr = w >> 1, wc = w & 1;
  const int m0 = blockIdx.y * 128, n0 = blockIdx.x * 128;
  __shared__ __align__(16) u16 As[2][128 * 32];
  __shared__ __align__(16) u16 Bs[2][128 * 32];
  const int r0 = t >> 2, cb = (t & 3) * 8;
  const u16* a0 = A + (size_t)(m0 + r0) * K + cb;
  const u16* b0 = Bt + (size_t)(n0 + r0) * K + cb;
  const size_t rowjmp = (size_t)64 * K;
  f32x4 acc[4][4] = {};

#define GSTAGE(bb, k0)                                      \
  {                                                         \
    GLDS16(a0 + (k0), &As[bb][t * 8]);                      \
    GLDS16(a0 + rowjmp + (k0), &As[bb][2048 + t * 8]);      \
    GLDS16(b0 + (k0), &Bs[bb][t * 8]);                      \
    GLDS16(b0 + rowjmp + (k0), &Bs[bb][2048 + t * 8]);      \
  }

  GSTAGE(0, 0);
  __syncthreads();
  for (int k0 = 0; k0 < K; k0 += 32) {
    const int bb = (k0 >> 5) & 1;
    if (k0 + 32 < K) GSTAGE(bb ^ 1, k0 + 32);
    bf16x8 a[4], b[4];
#pragma unroll
    for (int m = 0; m < 4; ++m)
      a[m] = *(const bf16x8*)&As[bb][(wr * 64 + m * 16 + lr) * 32 + lg * 8];
#pragma unroll
    for (int n = 0; n < 4; ++n)
      b[n] = *(const bf16x8*)&Bs[bb][(wc * 64 + n * 16 + lr) * 32 + lg * 8];
    __builtin_amdgcn_s_setprio(1);
#pragma unroll
    for (int m = 0; m < 4; ++m)
#pragma unroll
      for (int n = 0; n < 4; ++n)
        acc[m][n] =
            __builtin_amdgcn_mfma_f32_16x16x32_bf16(a[m], b[n], acc[m][n], 0, 0, 0);
    __builtin_amdgcn_s_setprio(0);
    __syncthreads();
  }
#undef GSTAGE

#pragma unroll
  for (int m = 0; m < 4; ++m) {
    int rowg = m0 + wr * 64 + m * 16 + lg * 4;
#pragma unroll
    for (int n = 0; n < 4; ++n) {
      int colg = n0 + wc * 64 + n * 16 + lr;
      if (MODE == 1) {
        float* C = (float*)Cp;
#pragma unroll
        for (int j = 0; j < 4; ++j)
          C[(size_t)(rowg + j) * N + colg] = acc[m][n][j];
      } else {
        if (colg < 1024) {  // Q: fold softmax scale (in exp2 domain)
          u16* C = (u16*)Cp;
#pragma unroll
          for (int j = 0; j < 4; ++j)
            C[(size_t)(rowg + j) * 2048 + colg] = f2bf(acc[m][n][j] * SC2F);
        } else if (colg < 2048) {  // K
          u16* C = (u16*)Cp;
#pragma unroll
          for (int j = 0; j < 4; ++j)
            C[(size_t)(rowg + j) * 2048 + colg] = f2bf(acc[m][n][j]);
        } else {  // V, stored transposed [dk_total][S]
          int vidx = colg - 2048, bb2 = rowg >> 11, s = rowg & 2047;
          u16x4 pk;
#pragma unroll
          for (int j = 0; j < 4; ++j) pk[j] = f2bf(acc[m][n][j]);
          *(u16x4*)(Vt + (size_t)(bb2 * 1024 + vidx) * 2048 + s) = pk;
        }
      }
    }
  }
}

// ---------------- flash attention (swapped QK^T, 2-phase KV pipeline) -----
// grid: 1024 blocks = (b,h) * 32 q-tiles of 64 rows; 4 waves * 16 q-rows.
// sacc = mfma(K_frag, Q_frag) => lane holds S[q=lr][k=16n+4lg+j];
// softmax state (m,l) per-lane scalar. Q pre-scaled by SC2F in GEMM.
__global__ __launch_bounds__(256) void attn(const u16* __restrict__ qkb,
                                            const u16* __restrict__ vtb,
                                            u16* __restrict__ hb) {
  const int t = threadIdx.x, lane = t & 63, w = t >> 6;
  const int lr = lane & 15, lg = lane >> 4;
  int blk = blockIdx.x;
  int qi = blk & 31, bh = blk >> 5;
  int b = bh >> 4, h = bh & 15;
  int q0 = qi * 64;
  __shared__ __align__(16) u16 Ks[2][64 * 64];   // [s][dk], chunk^=(s&7)
  __shared__ __align__(16) u16 Vts[2][64 * 64];  // [dk][s], chunk^=(d&7)
  __shared__ __align__(16) u32 Ps[4][16 * 36];   // per-wave packed P

  // Q fragment (B-operand): col=q=lr, k-slice = d
  const u16* qbase = qkb + (size_t)(b * 2048 + q0 + w * 16 + lr) * 2048 + h * 64;
  bf16x8 qf0 = *(const bf16x8*)(qbase + lg * 8);
  bf16x8 qf1 = *(const bf16x8*)(qbase + 32 + lg * 8);

  f32x4 oacc[4] = {};
  float mrun = -1e30f, lrun = 0.f;

  // hoisted swizzled LDS read offsets (same formula for K and V)
  int off[2][4];
#pragma unroll
  for (int kk = 0; kk < 2; ++kk)
#pragma unroll
    for (int n = 0; n < 4; ++n) {
      int s = n * 16 + lr;
      off[kk][n] = s * 64 + (((kk * 4 + lg) ^ (s & 7)) * 8);
    }

  // staging pointers: rows rr and rr+32, byte-swizzled source chunk
  const int rr = t >> 3, cbb = t & 7;
  const int swz = (cbb ^ (rr & 7)) * 8;
  const u16* Kg = qkb + (size_t)(b * 2048) * 2048 + 1024 + h * 64;
  const u16* Vg = vtb + (size_t)(b * 1024 + h * 64) * 2048;
  const u16* kp0 = Kg + (size_t)rr * 2048 + swz;
  const u16* vp0 = Vg + (size_t)rr * 2048 + swz;
  u32* Pw = &Ps[w][0];

#define ASTAGE(bb, tv)                                   \
  {                                                      \
    const u16* kp = kp0 + (size_t)(tv)*131072;           \
    const u16* vp = vp0 + (tv)*64;                       \
    GLDS16(kp, &Ks[bb][t * 8]);                          \
    GLDS16(kp + 65536, &Ks[bb][2048 + t * 8]);           \
    GLDS16(vp, &Vts[bb][t * 8]);                         \
    GLDS16(vp + 65536, &Vts[bb][2048 + t * 8]);          \
  }

  ASTAGE(0, 0);
  __syncthreads();

  for (int tv = 0; tv < 32; ++tv) {
    const int bb = tv & 1;
    if (tv < 31) ASTAGE(bb ^ 1, tv + 1);

    // S^T = K * Q^T
    f32x4 sacc[4] = {};
    __builtin_amdgcn_s_setprio(1);
#pragma unroll
    for (int kk = 0; kk < 2; ++kk) {
      bf16x8 qf = kk ? qf1 : qf0;
#pragma unroll
      for (int n = 0; n < 4; ++n) {
        bf16x8 kf = *(const bf16x8*)&Ks[bb][off[kk][n]];
        sacc[n] = __builtin_amdgcn_mfma_f32_16x16x32_bf16(kf, qf, sacc[n], 0, 0, 0);
      }
    }
    __builtin_amdgcn_s_setprio(0);

    // in-register online softmax (exp2 domain, scale pre-folded into Q)
    float pm = sacc[0][0];
#pragma unroll
    for (int n = 0; n < 4; ++n)
#pragma unroll
      for (int j = 0; j < 4; ++j) pm = fmaxf(pm, sacc[n][j]);
    pm = fmaxf(pm, __shfl_xor(pm, 16));
    pm = fmaxf(pm, __shfl_xor(pm, 32));

    if (__any(pm > mrun + 8.0f)) {  // T13 defer-max: rescale only when needed
      float mnew = fmaxf(mrun, pm);
      float al = __builtin_amdgcn_exp2f(mrun - mnew);
      lrun *= al;
      float alj[4];
#pragma unroll
      for (int j = 0; j < 4; ++j) alj[j] = __shfl(al, 4 * lg + j);
#pragma unroll
      for (int n = 0; n < 4; ++n)
#pragma unroll
        for (int j = 0; j < 4; ++j) oacc[n][j] *= alj[j];
      mrun = mnew;
    }

    float p[16], ps = 0.f;
#pragma unroll
    for (int n = 0; n < 4; ++n)
#pragma unroll
      for (int j = 0; j < 4; ++j) {
        float v = __builtin_amdgcn_exp2f(sacc[n][j] - mrun);
        p[n * 4 + j] = v;
        ps += v;
      }
    ps += __shfl_xor(ps, 16);
    ps += __shfl_xor(ps, 32);
    lrun += ps;

    // pack P: word idx = k/2 = 8n + 2lg + pp, row q = lr (stride 36 u32)
#pragma unroll
    for (int n = 0; n < 4; ++n)
#pragma unroll
      for (int pp = 0; pp < 2; ++pp)
        Pw[lr * 36 + 8 * n + 2 * lg + pp] =
            cvt_pk(p[n * 4 + 2 * pp], p[n * 4 + 2 * pp + 1]);

    // PV: A-frag = P[q=lr][k=32kk+8lg..+7]
    __builtin_amdgcn_s_setprio(1);
#pragma unroll
    for (int kk = 0; kk < 2; ++kk) {
      bf16x8 pa = *(const bf16x8*)&Pw[lr * 36 + 16 * kk + 4 * lg];
#pragma unroll
      for (int n = 0; n < 4; ++n) {
        bf16x8 vf = *(const bf16x8*)&Vts[bb][off[kk][n]];
        oacc[n] = __builtin_amdgcn_mfma_f32_16x16x32_bf16(pa, vf, oacc[n], 0, 0, 0);
      }
    }
    __builtin_amdgcn_s_setprio(0);
    __syncthreads();
  }
#undef ASTAGE

  float rinv = __builtin_amdgcn_rcpf(lrun);
  float rj[4];
#pragma unroll
  for (int j = 0; j < 4; ++j) rj[j] = __shfl(rinv, 4 * lg + j);
  int rowg = b * 2048 + q0 + w * 16 + lg * 4;
#pragma unroll
  for (int n = 0; n < 4; ++n) {
    int col = h * 64 + n * 16 + lr;
#pragma unroll
    for (int j = 0; j < 4; ++j)
      hb[(size_t)(rowg + j) * 1024 + col] = f2bf(oacc[n][j] * rj[j]);
  }
}

extern "C" void kernel_launch(void* const* d_in, const int* in_sizes, int n_in,
                              void* d_out, int out_size, void* d_ws,
                              size_t ws_size, hipStream_t stream) {
  const float* x = (const float*)d_in[0];
  const float* wq = (const float*)d_in[1];
  const float* wk = (const float*)d_in[2];
  const float* wv = (const float*)d_in[3];
  const float* wo = (const float*)d_in[4];

  u16* xb = (u16*)d_ws;              // [4096][1024]        4M
  u16* wqkv = xb + 4 * 1024 * 1024;  // [3072][1024]        3M
  u16* wot = wqkv + 3 * 1024 * 1024; // [1024][1024]        1M
  u16* qkb = wot + 1024 * 1024;      // [4096][2048] Q|K    8M
  u16* vtb = qkb + 8 * 1024 * 1024;  // [2][1024][2048] Vt  4M
  u16* hb = vtb + 4 * 1024 * 1024;   // [4096][1024] heads  4M

  cast_x<<<2048, 256, 0, stream>>>(x, xb);
  cast_wqkv<<<12288, 256, 0, stream>>>(wq, wk, wv, wqkv);
  cast_wo<<<4096, 256, 0, stream>>>(wo, wot);
  gemm_bt<2><<<dim3(24, 32), 256, 0, stream>>>(xb, wqkv, qkb, vtb, 4096, 3072, 1024);
  attn<<<1024, 256, 0, stream>>>(qkb, vtb, hb);
  gemm_bt<1><<<dim3(8, 32), 256, 0, stream>>>(hb, wot, d_out, nullptr, 4096, 1024, 1024);
}

// Round 4
// 154.147 us; speedup vs baseline: 1.1308x; 1.1308x over previous
//
#include <hip/hip_runtime.h>

typedef __attribute__((ext_vector_type(8))) short bf16x8;
typedef __attribute__((ext_vector_type(4))) float f32x4;
typedef __attribute__((ext_vector_type(4))) unsigned short u16x4;
typedef unsigned short u16;
typedef unsigned int u32;

static __device__ __forceinline__ u16 f2bf(float f) {
  u32 u = __float_as_uint(f);
  u32 r = (u + 0x7fffu + ((u >> 16) & 1u)) >> 16;  // RNE
  return (u16)r;
}

static __device__ __forceinline__ u32 cvt_pk(float lo, float hi) {
  u32 r;
  asm("v_cvt_pk_bf16_f32 %0, %1, %2" : "=v"(r) : "v"(lo), "v"(hi));
  return r;
}

#define GLDS16(g, l)                                                        \
  __builtin_amdgcn_global_load_lds(                                         \
      (const __attribute__((address_space(1))) u32*)(g),                    \
      (__attribute__((address_space(3))) u32*)(l), 16, 0, 0)

#define SC2F 0.18033688011112042f  // 0.125 * log2(e)

// ---------------- cast kernels ----------------
__global__ __launch_bounds__(256) void cast_x(const float* __restrict__ x,
                                              u16* __restrict__ xb) {
  int i = blockIdx.x * 256 + threadIdx.x;  // one thread per 8 elems
  const float4* xv = (const float4*)x;
  float4 a = xv[i * 2], b = xv[i * 2 + 1];
  bf16x8 o;
  o[0] = f2bf(a.x); o[1] = f2bf(a.y); o[2] = f2bf(a.z); o[3] = f2bf(a.w);
  o[4] = f2bf(b.x); o[5] = f2bf(b.y); o[6] = f2bf(b.z); o[7] = f2bf(b.w);
  *(bf16x8*)(xb + i * 8) = o;
}

// Wqkv_t[n][d], n = sel*1024 + h*64 + kk; value = W_sel[h][d][kk]
__global__ __launch_bounds__(256) void cast_wqkv(const float* __restrict__ wq,
                                                 const float* __restrict__ wk,
                                                 const float* __restrict__ wv,
                                                 u16* __restrict__ wt) {
  int tid = blockIdx.x * 256 + threadIdx.x;  // 3M
  int n = tid >> 10, d = tid & 1023;
  int sel = n >> 10, r = n & 1023, h = r >> 6, kk = r & 63;
  const float* src = sel == 0 ? wq : (sel == 1 ? wk : wv);
  wt[tid] = f2bf(src[h * 65536 + d * 64 + kk]);
}

// WOt[n][k] = W_O[k][n]
__global__ __launch_bounds__(256) void cast_wo(const float* __restrict__ wo,
                                               u16* __restrict__ wt) {
  int tid = blockIdx.x * 256 + threadIdx.x;  // 1M
  int n = tid >> 10, k = tid & 1023;
  wt[tid] = f2bf(wo[k * 1024 + n]);
}

// ---------------- GEMM: C = A(bf16)[M,K] * Bt(bf16)[N,K]^T ----------------
// 2-phase double-buffered staging (issue-early, one barrier per K-step).
// MODE 1: float C [M,N].  MODE 2: col<1024 -> Q*SC2F bf16; col<2048 -> K bf16;
//          col>=2048 -> Vt[(b*1024 + (col-2048))*2048 + s], row = b*2048+s.
template <int MODE>
__global__ __launch_bounds__(256) void gemm_bt(const u16* __restrict__ A,
                                               const u16* __restrict__ Bt,
                                               void* __restrict__ Cp,
                                               u16* __restrict__ Vt, int M,
                                               int N, int K) {
  const int t = threadIdx.x;
  const int lane = t & 63, w = t >> 6;
  const int lr = lane & 15, lg = lane >> 4;
  const int wr = w >> 1, wc = w & 1;
  const int m0 = blockIdx.y * 128, n0 = blockIdx.x * 128;
  __shared__ __align__(16) u16 As[2][128 * 32];
  __shared__ __align__(16) u16 Bs[2][128 * 32];
  const int r0 = t >> 2, cb = (t & 3) * 8;
  const u16* a0 = A + (size_t)(m0 + r0) * K + cb;
  const u16* b0 = Bt + (size_t)(n0 + r0) * K + cb;
  const size_t rowjmp = (size_t)64 * K;
  f32x4 acc[4][4] = {};

#define GSTAGE(bb, k0)                                      \
  {                                                         \
    GLDS16(a0 + (k0), &As[bb][t * 8]);                      \
    GLDS16(a0 + rowjmp + (k0), &As[bb][2048 + t * 8]);      \
    GLDS16(b0 + (k0), &Bs[bb][t * 8]);                      \
    GLDS16(b0 + rowjmp + (k0), &Bs[bb][2048 + t * 8]);      \
  }

  GSTAGE(0, 0);
  __syncthreads();
  for (int k0 = 0; k0 < K; k0 += 32) {
    const int bb = (k0 >> 5) & 1;
    if (k0 + 32 < K) GSTAGE(bb ^ 1, k0 + 32);
    bf16x8 a[4], b[4];
#pragma unroll
    for (int m = 0; m < 4; ++m)
      a[m] = *(const bf16x8*)&As[bb][(wr * 64 + m * 16 + lr) * 32 + lg * 8];
#pragma unroll
    for (int n = 0; n < 4; ++n)
      b[n] = *(const bf16x8*)&Bs[bb][(wc * 64 + n * 16 + lr) * 32 + lg * 8];
    __builtin_amdgcn_s_setprio(1);
#pragma unroll
    for (int m = 0; m < 4; ++m)
#pragma unroll
      for (int n = 0; n < 4; ++n)
        acc[m][n] =
            __builtin_amdgcn_mfma_f32_16x16x32_bf16(a[m], b[n], acc[m][n], 0, 0, 0);
    __builtin_amdgcn_s_setprio(0);
    __syncthreads();
  }
#undef GSTAGE

#pragma unroll
  for (int m = 0; m < 4; ++m) {
    int rowg = m0 + wr * 64 + m * 16 + lg * 4;
#pragma unroll
    for (int n = 0; n < 4; ++n) {
      int colg = n0 + wc * 64 + n * 16 + lr;
      if (MODE == 1) {
        float* C = (float*)Cp;
#pragma unroll
        for (int j = 0; j < 4; ++j)
          C[(size_t)(rowg + j) * N + colg] = acc[m][n][j];
      } else {
        if (colg < 1024) {  // Q: fold softmax scale (exp2 domain)
          u16* C = (u16*)Cp;
#pragma unroll
          for (int j = 0; j < 4; ++j)
            C[(size_t)(rowg + j) * 2048 + colg] = f2bf(acc[m][n][j] * SC2F);
        } else if (colg < 2048) {  // K
          u16* C = (u16*)Cp;
#pragma unroll
          for (int j = 0; j < 4; ++j)
            C[(size_t)(rowg + j) * 2048 + colg] = f2bf(acc[m][n][j]);
        } else {  // V, stored transposed [dk_total][S]
          int vidx = colg - 2048, bb2 = rowg >> 11, s = rowg & 2047;
          u16x4 pk;
#pragma unroll
          for (int j = 0; j < 4; ++j) pk[j] = f2bf(acc[m][n][j]);
          *(u16x4*)(Vt + (size_t)(bb2 * 1024 + vidx) * 2048 + s) = pk;
        }
      }
    }
  }
}

// ---------------- flash attention (swapped QK^T, 2-phase KV pipeline) -----
// grid: 1024 blocks = (b,h) * 32 q-tiles of 64 rows; 4 waves * 16 q-rows.
// sacc = mfma(K_frag, Q_frag) => lane holds S[q=lr][k=16n+4lg+j];
// softmax state (m,l) per-lane scalar. Q pre-scaled by SC2F in GEMM.
// LDS = 16K (K dbuf) + 16K (V dbuf) + 8K (Ps, XOR-swizzled) = 40960 B
// => exactly 4 blocks/CU.
__global__ __launch_bounds__(256) void attn(const u16* __restrict__ qkb,
                                            const u16* __restrict__ vtb,
                                            u16* __restrict__ hb) {
  const int t = threadIdx.x, lane = t & 63, w = t >> 6;
  const int lr = lane & 15, lg = lane >> 4;
  int blk = blockIdx.x;
  int qi = blk & 31, bh = blk >> 5;
  int b = bh >> 4, h = bh & 15;
  int q0 = qi * 64;
  __shared__ __align__(16) u16 Ks[2][64 * 64];   // [s][dk], chunk^=(s&7)
  __shared__ __align__(16) u16 Vts[2][64 * 64];  // [dk][s], chunk^=(d&7)
  __shared__ __align__(16) u32 Ps[4][16 * 32];   // per-wave packed P, swizzled

  // Q fragment (B-operand): col=q=lr, k-slice = d
  const u16* qbase = qkb + (size_t)(b * 2048 + q0 + w * 16 + lr) * 2048 + h * 64;
  bf16x8 qf0 = *(const bf16x8*)(qbase + lg * 8);
  bf16x8 qf1 = *(const bf16x8*)(qbase + 32 + lg * 8);

  f32x4 oacc[4] = {};
  float mrun = -1e30f, lrun = 0.f;

  // hoisted swizzled LDS read offsets (same formula for K and V)
  int off[2][4];
#pragma unroll
  for (int kk = 0; kk < 2; ++kk)
#pragma unroll
    for (int n = 0; n < 4; ++n) {
      int s = n * 16 + lr;
      off[kk][n] = s * 64 + (((kk * 4 + lg) ^ (s & 7)) * 8);
    }
  const int xw = (lr & 7) << 2;  // Ps word-swizzle

  // staging pointers: rows rr and rr+32, byte-swizzled source chunk
  const int rr = t >> 3, cbb = t & 7;
  const int swz = (cbb ^ (rr & 7)) * 8;
  const u16* Kg = qkb + (size_t)(b * 2048) * 2048 + 1024 + h * 64;
  const u16* Vg = vtb + (size_t)(b * 1024 + h * 64) * 2048;
  const u16* kp0 = Kg + (size_t)rr * 2048 + swz;
  const u16* vp0 = Vg + (size_t)rr * 2048 + swz;
  u32* Pw = &Ps[w][0];

#define ASTAGE(bb, tv)                                   \
  {                                                      \
    const u16* kp = kp0 + (size_t)(tv)*131072;           \
    const u16* vp = vp0 + (tv)*64;                       \
    GLDS16(kp, &Ks[bb][t * 8]);                          \
    GLDS16(kp + 65536, &Ks[bb][2048 + t * 8]);           \
    GLDS16(vp, &Vts[bb][t * 8]);                         \
    GLDS16(vp + 65536, &Vts[bb][2048 + t * 8]);          \
  }

  ASTAGE(0, 0);
  __syncthreads();

  for (int tv = 0; tv < 32; ++tv) {
    const int bb = tv & 1;
    if (tv < 31) ASTAGE(bb ^ 1, tv + 1);

    // S^T = K * Q^T
    f32x4 sacc[4] = {};
    __builtin_amdgcn_s_setprio(1);
#pragma unroll
    for (int kk = 0; kk < 2; ++kk) {
      bf16x8 qf = kk ? qf1 : qf0;
#pragma unroll
      for (int n = 0; n < 4; ++n) {
        bf16x8 kf = *(const bf16x8*)&Ks[bb][off[kk][n]];
        sacc[n] = __builtin_amdgcn_mfma_f32_16x16x32_bf16(kf, qf, sacc[n], 0, 0, 0);
      }
    }
    __builtin_amdgcn_s_setprio(0);

    // in-register online softmax (exp2 domain, scale pre-folded into Q)
    float pm = sacc[0][0];
#pragma unroll
    for (int n = 0; n < 4; ++n)
#pragma unroll
      for (int j = 0; j < 4; ++j) pm = fmaxf(pm, sacc[n][j]);
    pm = fmaxf(pm, __shfl_xor(pm, 16));
    pm = fmaxf(pm, __shfl_xor(pm, 32));

    if (__any(pm > mrun + 8.0f)) {  // T13 defer-max
      float mnew = fmaxf(mrun, pm);
      float al = __builtin_amdgcn_exp2f(mrun - mnew);
      lrun *= al;
      float alj[4];
#pragma unroll
      for (int j = 0; j < 4; ++j) alj[j] = __shfl(al, 4 * lg + j);
#pragma unroll
      for (int n = 0; n < 4; ++n)
#pragma unroll
        for (int j = 0; j < 4; ++j) oacc[n][j] *= alj[j];
      mrun = mnew;
    }

    float p[16], ps = 0.f;
#pragma unroll
    for (int n = 0; n < 4; ++n)
#pragma unroll
      for (int j = 0; j < 4; ++j) {
        float v = __builtin_amdgcn_exp2f(sacc[n][j] - mrun);
        p[n * 4 + j] = v;
        ps += v;
      }
    ps += __shfl_xor(ps, 16);
    ps += __shfl_xor(ps, 32);
    lrun += ps;

    // pack P: logical word = 8n+2lg+pp (row q=lr, stride 32 u32),
    // physical word = logical ^ xw (bank-spread; b128 reads stay aligned)
#pragma unroll
    for (int n = 0; n < 4; ++n)
#pragma unroll
      for (int pp = 0; pp < 2; ++pp)
        Pw[lr * 32 + ((8 * n + 2 * lg + pp) ^ xw)] =
            cvt_pk(p[n * 4 + 2 * pp], p[n * 4 + 2 * pp + 1]);

    // PV: A-frag = P[q=lr][k=32kk+8lg..+7] = logical words [16kk+4lg, +4)
    __builtin_amdgcn_s_setprio(1);
#pragma unroll
    for (int kk = 0; kk < 2; ++kk) {
      bf16x8 pa = *(const bf16x8*)&Pw[lr * 32 + ((16 * kk + 4 * lg) ^ xw)];
#pragma unroll
      for (int n = 0; n < 4; ++n) {
        bf16x8 vf = *(const bf16x8*)&Vts[bb][off[kk][n]];
        oacc[n] = __builtin_amdgcn_mfma_f32_16x16x32_bf16(pa, vf, oacc[n], 0, 0, 0);
      }
    }
    __builtin_amdgcn_s_setprio(0);
    __syncthreads();
  }
#undef ASTAGE

  float rinv = __builtin_amdgcn_rcpf(lrun);
  float rj[4];
#pragma unroll
  for (int j = 0; j < 4; ++j) rj[j] = __shfl(rinv, 4 * lg + j);
  int rowg = b * 2048 + q0 + w * 16 + lg * 4;
#pragma unroll
  for (int n = 0; n < 4; ++n) {
    int col = h * 64 + n * 16 + lr;
#pragma unroll
    for (int j = 0; j < 4; ++j)
      hb[(size_t)(rowg + j) * 1024 + col] = f2bf(oacc[n][j] * rj[j]);
  }
}

extern "C" void kernel_launch(void* const* d_in, const int* in_sizes, int n_in,
                              void* d_out, int out_size, void* d_ws,
                              size_t ws_size, hipStream_t stream) {
  const float* x = (const float*)d_in[0];
  const float* wq = (const float*)d_in[1];
  const float* wk = (const float*)d_in[2];
  const float* wv = (const float*)d_in[3];
  const float* wo = (const float*)d_in[4];

  u16* xb = (u16*)d_ws;              // [4096][1024]        4M
  u16* wqkv = xb + 4 * 1024 * 1024;  // [3072][1024]        3M
  u16* wot = wqkv + 3 * 1024 * 1024; // [1024][1024]        1M
  u16* qkb = wot + 1024 * 1024;      // [4096][2048] Q|K    8M
  u16* vtb = qkb + 8 * 1024 * 1024;  // [2][1024][2048] Vt  4M
  u16* hb = vtb + 4 * 1024 * 1024;   // [4096][1024] heads  4M

  cast_x<<<2048, 256, 0, stream>>>(x, xb);
  cast_wqkv<<<12288, 256, 0, stream>>>(wq, wk, wv, wqkv);
  cast_wo<<<4096, 256, 0, stream>>>(wo, wot);
  gemm_bt<2><<<dim3(24, 32), 256, 0, stream>>>(xb, wqkv, qkb, vtb, 4096, 3072, 1024);
  attn<<<1024, 256, 0, stream>>>(qkb, vtb, hb);
  gemm_bt<1><<<dim3(8, 32), 256, 0, stream>>>(hb, wot, d_out, nullptr, 4096, 1024, 1024);
}